// Round 6
// baseline (20900.600 us; speedup 1.0000x reference)
//
#include <hip/hip_runtime.h>
#include <math.h>

#define TSTEPS 100
#define BB 256
#define FF 1024
#define NIN 784
#define NW 13           // 13*64 = 832 >= 784 bits per input row
#define CAPA 192        // max pre-spikes per (t,b)
#define CAPB 128        // max pre-spikes per (t,i)
#define NBLK 2048       // persistent grid: 8 blocks/CU, co-resident by capacity

typedef unsigned long long u64;

// ---------- one-time init ----------
__global__ __launch_bounds__(256) void k_init(
    const float* __restrict__ W, float* __restrict__ wT,
    float* __restrict__ apre_rep, u64* __restrict__ spkT,
    unsigned* __restrict__ bar)
{
    int idx = blockIdx.x * 256 + threadIdx.x;          // covers NIN*FF = 802816
    {
        int f = idx & (FF - 1);
        int i = idx >> 10;
        wT[idx] = W[f * NIN + i];                      // wT[i][f] = W[f][i]
    }
    apre_rep[idx] = 0.f;                               // 8 copies = 2*802816 elems
    apre_rep[idx + NIN * FF] = 0.f;
    if (idx < 2 * FF * 4) spkT[idx] = 0ull;
    if (idx < 1024) bar[idx] = 0u;
}

// ---------- Poisson encode (pure f32): p = image*0.2f; noise < p ----------
__global__ __launch_bounds__(256) void k_encode(
    const float* __restrict__ image, const float* __restrict__ noise,
    u64* __restrict__ prebits)
{
    int tid = blockIdx.x * 256 + threadIdx.x;
    int lane = threadIdx.x & 63;
    int word = tid >> 6;           // (t*BB + b)*NW + wd
    int wd = word % NW;
    int tb = word / NW;
    int b = tb & (BB - 1);
    int i = (wd << 6) + lane;
    bool s = false;
    if (i < NIN) {
        float pf = __fmul_rn(image[b * NIN + i], 0.2f);
        s = (noise[(size_t)tb * NIN + i] < pf);
    }
    u64 m = __ballot(s);
    if (lane == 0) prebits[word] = m;
}

// ---------- transposed prebits: prebitsT[t][i][wb] (bit = batch b) ----------
__global__ __launch_bounds__(256) void k_encode_t(
    const u64* __restrict__ prebits, u64* __restrict__ prebitsT)
{
    int tid = blockIdx.x * 256 + threadIdx.x;
    int b = tid & (BB - 1);
    int ti = tid >> 8;             // t*NIN + i
    int i = ti % NIN;
    int t = ti / NIN;
    u64 w = prebits[((size_t)t * BB + b) * NW + (i >> 6)];
    bool s = (w >> (i & 63)) & 1ull;
    u64 m = __ballot(s);
    if ((threadIdx.x & 63) == 0)
        prebitsT[(size_t)ti * 4 + ((threadIdx.x >> 6) & 3)] = m;
}

// ---------- index lists per (t,b): ascending i, KC=384 chunk marks ----------
__global__ __launch_bounds__(256) void k_lists(
    const u64* __restrict__ prebits, unsigned short* __restrict__ idxA,
    unsigned short* __restrict__ cntA)
{
    int tb = blockIdx.x * 256 + threadIdx.x;
    const u64* pb = prebits + (size_t)tb * NW;
    unsigned short* ia = idxA + (size_t)tb * CAPA;
    int n = 0, c1 = 0, c2 = 0;
    for (int wd = 0; wd < NW; ++wd) {
        u64 m = pb[wd];
        int boff = wd << 6;
        while (m) {
            int j = __builtin_ctzll(m); m &= m - 1;
            if (n < CAPA) ia[n] = (unsigned short)(boff + j);
            ++n;
        }
        if (wd == 5)  c1 = n;     // i < 384 boundary
        if (wd == 11) c2 = n;     // i < 768 boundary
    }
    if (n > CAPA) n = CAPA;
    if (c2 > n) c2 = n;
    if (c1 > c2) c1 = c2;
    cntA[tb * 4 + 0] = (unsigned short)c1;
    cntA[tb * 4 + 1] = (unsigned short)c2;
    cntA[tb * 4 + 2] = (unsigned short)n;
}

// ---------- b-lists per (t,i): ascending b ----------
__global__ __launch_bounds__(256) void k_listsT(
    const u64* __restrict__ prebitsT, unsigned char* __restrict__ idxB,
    unsigned short* __restrict__ cntB)
{
    int ti = blockIdx.x * 256 + threadIdx.x;
    if (ti >= TSTEPS * NIN) return;
    const u64* pt = prebitsT + (size_t)ti * 4;
    unsigned char* ib = idxB + (size_t)ti * CAPB;
    int n = 0;
    for (int wb = 0; wb < 4; ++wb) {
        u64 m = pt[wb];
        int boff = wb << 6;
        while (m) {
            int j = __builtin_ctzll(m); m &= m - 1;
            if (n < CAPB) ib[n] = (unsigned char)(boff + j);
            ++n;
        }
    }
    cntB[ti] = (unsigned short)(n > CAPB ? CAPB : n);
}

// ---------- 2-level grid barrier (monotonic epochs, device-scope) ----------
// bar layout (u32): [leaf*32] 8 leaf counters, [256] root, [512+leaf*32] 8 flags
__device__ __forceinline__ void grid_bar(unsigned* bar, int bid, unsigned ep1)
{
    __syncthreads();
    if (threadIdx.x == 0) {
        int leaf = bid & 7;
        __threadfence();   // release this block's stores
        unsigned v = __hip_atomic_fetch_add(bar + leaf * 32, 1u,
                        __ATOMIC_RELAXED, __HIP_MEMORY_SCOPE_AGENT);
        if (v == 256u * ep1 - 1u) {                 // last arrival of this leaf
            __threadfence();
            unsigned r = __hip_atomic_fetch_add(bar + 256, 1u,
                            __ATOMIC_RELAXED, __HIP_MEMORY_SCOPE_AGENT);
            if (r == 8u * ep1 - 1u) {               // global last
                __threadfence();
                #pragma unroll
                for (int x = 0; x < 8; ++x)
                    __hip_atomic_store(bar + 512 + x * 32, ep1,
                        __ATOMIC_RELAXED, __HIP_MEMORY_SCOPE_AGENT);
            }
        }
        while (__hip_atomic_load(bar + 512 + leaf * 32,
                   __ATOMIC_RELAXED, __HIP_MEMORY_SCOPE_AGENT) < ep1)
            __builtin_amdgcn_s_sleep(8);
        __threadfence();   // acquire others' stores
    }
    __syncthreads();
}

// ---------- persistent kernel: all 100 steps, 199 grid barriers ----------
__global__ __launch_bounds__(128, 4) void k_run(
    float* __restrict__ wT, float* __restrict__ apre_rep, float* __restrict__ apost,
    const u64* __restrict__ prebits,
    const unsigned short* __restrict__ idxA, const unsigned short* __restrict__ cntA,
    const unsigned char* __restrict__ idxB, const unsigned short* __restrict__ cntB,
    u64* __restrict__ spkT, float* __restrict__ out, unsigned* __restrict__ bar,
    float dmem, float dpre, float dpost, float lrp, float lrm)
{
    int bid = blockIdx.x;            // 0..2047
    int g = bid & 7;                 // f-group (XCD-pinned under %8 round-robin)
    int b = bid >> 3;                // 0..255
    int f = (g << 7) | threadIdx.x;
    int tid = (b << 10) | f;

    // register-resident per-(b,f) state (only this thread/wave ever reads these)
    float memv = 0.f, cntv = 0.f, apov = 0.f;
    u64 prev_bal = 0ull;             // this wave's spike ballot from t-1
    unsigned ep = 1;

    for (int t = 0; t < TSTEPS; ++t) {
        u64* cur = spkT + (size_t)(t & 1) * FF * 4;
        u64* nxt = spkT + (size_t)((t + 1) & 1) * FF * 4;

        // ===== phase A =====
        // apost = f32(f32(apost*decay) + spk_{t-1})
        float spk_prev = (float)((prev_bal >> (threadIdx.x & 63)) & 1ull);
        apov = __fadd_rn(__fmul_rn(apov, dpost), spk_prev);
        apost[tid] = apov;                         // store-only; B reads it

        // I = ((chunk0 + chunk1) + chunk2), sequential f32 folds, ascending i
        const unsigned short* ia = idxA + (size_t)(t * BB + b) * CAPA;
        const unsigned short* ca = cntA + (size_t)(t * BB + b) * 4;
        int c1 = ca[0], c2 = ca[1], c3 = ca[2];
        float I = 0.0f;
        int k = 0;
        {
            float c = 0.0f;
            #pragma unroll 4
            for (; k < c1; ++k) c = __fadd_rn(c, wT[((int)ia[k] << 10) + f]);
            I = __fadd_rn(I, c);
        }
        {
            float c = 0.0f;
            #pragma unroll 4
            for (; k < c2; ++k) c = __fadd_rn(c, wT[((int)ia[k] << 10) + f]);
            I = __fadd_rn(I, c);
        }
        {
            float c = 0.0f;
            #pragma unroll 4
            for (; k < c3; ++k) c = __fadd_rn(c, wT[((int)ia[k] << 10) + f]);
            I = __fadd_rn(I, c);
        }

        float mm = __fadd_rn(__fmul_rn(memv, dmem), I);
        bool spk = (mm >= 16.0f);
        memv = spk ? 0.0f : mm;
        if (spk) {
            cntv += 1.0f;
            atomicOr(&cur[(f << 2) | (b >> 6)], 1ull << (b & 63));
        }
        prev_bal = __ballot(spk);
        if (threadIdx.x < 2) nxt[bid * 2 + threadIdx.x] = 0ull;  // zero next parity

        // apre update (replicated copy g), contiguous chunk [b*784,(b+1)*784)
        float* ap = apre_rep + (size_t)g * (BB * NIN);
        for (int e = b * NIN + threadIdx.x; e < (b + 1) * NIN; e += 128) {
            int bb = e & (BB - 1), ii = e >> 8;
            u64 w = prebits[((size_t)t * BB + bb) * NW + (ii >> 6)];
            float pr = (float)((w >> (ii & 63)) & 1ull);
            ap[e] = __fadd_rn(__fmul_rn(ap[e], dpre), pr);
        }

        grid_bar(bar, bid, ep); ++ep;

        // ===== phase B (skip at t=99) =====
        if (t < TSTEPS - 1) {
            // post-spike masks for column f (same for all i) — hoist
            u64 m0 = cur[(f << 2) | 0], m1 = cur[(f << 2) | 1];
            u64 m2 = cur[(f << 2) | 2], m3 = cur[(f << 2) | 3];
            for (int i = b; i < NIN; i += BB) {
                // Sm = fold_{b' in pre(i)} apost[b',f], ascending b'
                const unsigned char* ib = idxB + (size_t)(t * NIN + i) * CAPB;
                int cb = cntB[t * NIN + i];
                float Sm = 0.0f;
                #pragma unroll 4
                for (int k2 = 0; k2 < cb; ++k2)
                    Sm = __fadd_rn(Sm, apost[((int)ib[k2] << 10) + f]);
                // Sp = fold_{b' in spk(f)} apre[b',i], ascending b'
                const float* ar = apre_rep + (size_t)g * (BB * NIN) + (i << 8);
                float Sp = 0.0f;
                u64 mm0 = m0;
                while (mm0) { int j = __builtin_ctzll(mm0); mm0 &= mm0 - 1; Sp = __fadd_rn(Sp, ar[j]); }
                u64 mm1 = m1;
                while (mm1) { int j = __builtin_ctzll(mm1); mm1 &= mm1 - 1; Sp = __fadd_rn(Sp, ar[64 + j]); }
                u64 mm2 = m2;
                while (mm2) { int j = __builtin_ctzll(mm2); mm2 &= mm2 - 1; Sp = __fadd_rn(Sp, ar[128 + j]); }
                u64 mm3 = m3;
                while (mm3) { int j = __builtin_ctzll(mm3); mm3 &= mm3 - 1; Sp = __fadd_rn(Sp, ar[192 + j]); }

                int wi = (i << 10) | f;
                float w = wT[wi];
                w = __fadd_rn(w, __fmul_rn(lrp, Sp));
                w = __fsub_rn(w, __fmul_rn(lrm, Sm));
                w = fminf(fmaxf(w, 0.0f), 1.0f);
                wT[wi] = w;
            }
            grid_bar(bar, bid, ep); ++ep;
        }
    }

    out[tid] = cntv;    // spike counts, exact small ints
}

extern "C" void kernel_launch(void* const* d_in, const int* in_sizes, int n_in,
                              void* d_out, int out_size, void* d_ws, size_t ws_size,
                              hipStream_t stream)
{
    const float* image = (const float*)d_in[0];
    const float* W     = (const float*)d_in[1];
    const float* noise = (const float*)d_in[2];
    float* out = (float*)d_out;

    char* p = (char*)d_ws;
    float* wT       = (float*)p; p += (size_t)NIN * FF * 4;             // 3.2 MB
    float* apre_rep = (float*)p; p += (size_t)8 * BB * NIN * 4;         // 6.4 MB
    float* apost    = (float*)p; p += (size_t)BB * FF * 4;              // 1 MB
    u64* prebits    = (u64*)p;   p += (size_t)TSTEPS * BB * NW * 8;     // 2.66 MB
    u64* prebitsT   = (u64*)p;   p += (size_t)TSTEPS * NIN * 4 * 8;     // 2.5 MB
    u64* spkT       = (u64*)p;   p += (size_t)2 * FF * 4 * 8;           // 64 KB
    unsigned short* idxA = (unsigned short*)p; p += (size_t)TSTEPS * BB * CAPA * 2;
    unsigned short* cntA = (unsigned short*)p; p += (size_t)TSTEPS * BB * 4 * 2;
    unsigned char*  idxB = (unsigned char*)p;  p += (size_t)TSTEPS * NIN * CAPB;
    unsigned short* cntB = (unsigned short*)p; p += (size_t)TSTEPS * NIN * 2;
    unsigned* bar        = (unsigned*)p;       p += 1024 * 4;

    float dmem = (float)exp(-1.0 / 20.0);   // np.float32(np.exp(-0.05))
    float dpre = dmem, dpost = dmem;
    float lrp = (float)(0.01 / 256.0);
    float lrm = (float)(0.012 / 256.0);

    k_init<<<(NIN * FF) / 256, 256, 0, stream>>>(W, wT, apre_rep, spkT, bar);
    k_encode<<<(TSTEPS * BB * NW * 64) / 256, 256, 0, stream>>>(image, noise, prebits);
    k_encode_t<<<(TSTEPS * NIN * BB) / 256, 256, 0, stream>>>(prebits, prebitsT);
    k_lists<<<(TSTEPS * BB) / 256, 256, 0, stream>>>(prebits, idxA, cntA);
    k_listsT<<<(TSTEPS * NIN + 255) / 256, 256, 0, stream>>>(prebitsT, idxB, cntB);

    k_run<<<NBLK, 128, 0, stream>>>(
        wT, apre_rep, apost, prebits, idxA, cntA, idxB, cntB,
        spkT, out, bar, dmem, dpre, dpost, lrp, lrm);
}

// Round 7
// 8585.514 us; speedup vs baseline: 2.4344x; 2.4344x over previous
//
#include <hip/hip_runtime.h>
#include <math.h>

#define TSTEPS 100
#define BB 256
#define FF 1024
#define NIN 784
#define NW 13           // 13*64 = 832 >= 784 bits per input row

typedef unsigned long long u64;

// ---------- Poisson encode (pure f32): p = image*0.2f; noise < p ----------
__global__ __launch_bounds__(256) void k_encode(
    const float* __restrict__ image, const float* __restrict__ noise,
    u64* __restrict__ prebits)
{
    int tid = blockIdx.x * 256 + threadIdx.x;
    int lane = threadIdx.x & 63;
    int word = tid >> 6;           // (t*BB + b)*NW + wd
    int wd = word % NW;
    int tb = word / NW;
    int b = tb & (BB - 1);
    int i = (wd << 6) + lane;
    bool s = false;
    if (i < NIN) {
        float pf = __fmul_rn(image[b * NIN + i], 0.2f);   // single f32 rounding
        s = (noise[(size_t)tb * NIN + i] < pf);           // f32 compare
    }
    u64 m = __ballot(s);
    if (lane == 0) prebits[word] = m;
}

// ---------- transposed prebits: prebitsT[t][i][wb] (bit = batch b) ----------
__global__ __launch_bounds__(256) void k_encode_t(
    const u64* __restrict__ prebits, u64* __restrict__ prebitsT)
{
    int tid = blockIdx.x * 256 + threadIdx.x;
    int b = tid & (BB - 1);
    int ti = tid >> 8;             // t*NIN + i
    int i = ti % NIN;
    int t = ti / NIN;
    u64 w = prebits[((size_t)t * BB + b) * NW + (i >> 6)];
    bool s = (w >> (i & 63)) & 1ull;
    u64 m = __ballot(s);
    if ((threadIdx.x & 63) == 0)
        prebitsT[(size_t)ti * 4 + ((threadIdx.x >> 6) & 3)] = m;
}

// ---------- precompute apre_all[t][b][i] (input-only recurrence, f32-exact) ----------
__global__ __launch_bounds__(256) void k_apre(
    const u64* __restrict__ prebits, float* __restrict__ apre_all, float dpre)
{
    int e = blockIdx.x * 256 + threadIdx.x;    // < BB*NIN = 200704
    int b = e / NIN, i = e - b * NIN;
    float v = 0.f;
    for (int t = 0; t < TSTEPS; ++t) {
        u64 w = prebits[((size_t)t * BB + b) * NW + (i >> 6)];
        float pr = (float)((w >> (i & 63)) & 1ull);
        v = __fadd_rn(__fmul_rn(v, dpre), pr);            // apre = f32(apre*d + pre)
        apre_all[(size_t)t * (BB * NIN) + e] = v;         // coalesced store
    }
}

// ---------- the whole simulation: 1024 independent per-f-column blocks ----------
// Block f owns w[:,f] (LDS), apost[:,f] (LDS), mem/cnt (regs). No grid sync.
__global__ __launch_bounds__(256) void k_sim(
    const float* __restrict__ Wg, const u64* __restrict__ prebits,
    const u64* __restrict__ prebitsT, const float* __restrict__ apre_all,
    float* __restrict__ out,
    float dmem, float dpost, float lrp, float lrm)
{
    int f = blockIdx.x;            // 0..1023
    int b = threadIdx.x;           // 0..255

    __shared__ float wv[NIN];      // w column f  (3.1 KB)
    __shared__ float apo[BB];      // apost column f (1 KB)
    __shared__ u64 smask[4];       // spk(t) bitmask over b

    for (int i = b; i < NIN; i += 256) wv[i] = Wg[f * NIN + i];  // W[f][i], coalesced
    float memv = 0.f, cntv = 0.f, apov = 0.f;
    u64 prev_bal = 0ull;           // this wave's spike ballot from t-1
    __syncthreads();

    for (int t = 0; t < TSTEPS; ++t) {
        // ===== phase A (thread = b) =====
        // apost = f32(f32(apost*decay) + spk_{t-1})   (own wave's prev ballot)
        apov = __fadd_rn(__fmul_rn(apov, dpost),
                         (float)((prev_bal >> (b & 63)) & 1ull));
        apo[b] = apov;

        // I = ((chunk0 + chunk1) + chunk2): sequential f32 folds, ascending i,
        // KC=384 chunks = words {0..5},{6..11},{12} — identical to round-4 order.
        const u64* pb = prebits + ((size_t)t * BB + b) * NW;
        u64 pw[NW];
        #pragma unroll
        for (int wd = 0; wd < NW; ++wd) pw[wd] = pb[wd];

        float I = 0.0f;
        {
            float c = 0.0f;
            #pragma unroll
            for (int wd = 0; wd < 6; ++wd) {
                u64 m = pw[wd]; int base = wd << 6;
                while (m) { int j = __builtin_ctzll(m); m &= m - 1;
                            c = __fadd_rn(c, wv[base + j]); }
            }
            I = __fadd_rn(I, c);
        }
        {
            float c = 0.0f;
            #pragma unroll
            for (int wd = 6; wd < 12; ++wd) {
                u64 m = pw[wd]; int base = wd << 6;
                while (m) { int j = __builtin_ctzll(m); m &= m - 1;
                            c = __fadd_rn(c, wv[base + j]); }
            }
            I = __fadd_rn(I, c);
        }
        {
            float c = 0.0f;
            u64 m = pw[12];
            while (m) { int j = __builtin_ctzll(m); m &= m - 1;
                        c = __fadd_rn(c, wv[768 + j]); }
            I = __fadd_rn(I, c);
        }

        float mm = __fadd_rn(__fmul_rn(memv, dmem), I);
        bool spk = (mm >= 16.0f);
        memv = spk ? 0.0f : mm;
        if (spk) cntv += 1.0f;
        u64 bal = __ballot(spk);
        prev_bal = bal;
        if ((b & 63) == 0) smask[b >> 6] = bal;
        __syncthreads();               // apo/smask visible to phase B

        // ===== phase B: w column update (skip at t=99, unused for output) =====
        if (t < TSTEPS - 1) {
            u64 s0 = smask[0], s1 = smask[1], s2 = smask[2], s3 = smask[3];
            const float* at = apre_all + (size_t)t * (BB * NIN);
            for (int i = b; i < NIN; i += 256) {
                // Sm = fold_{b' in pre(i)} apost[b',f], ascending b'
                const u64* pt = prebitsT + ((size_t)t * NIN + i) * 4;
                u64 q0 = pt[0], q1 = pt[1], q2 = pt[2], q3 = pt[3];
                float Sm = 0.0f;
                while (q0) { int j = __builtin_ctzll(q0); q0 &= q0 - 1; Sm = __fadd_rn(Sm, apo[j]); }
                while (q1) { int j = __builtin_ctzll(q1); q1 &= q1 - 1; Sm = __fadd_rn(Sm, apo[64 + j]); }
                while (q2) { int j = __builtin_ctzll(q2); q2 &= q2 - 1; Sm = __fadd_rn(Sm, apo[128 + j]); }
                while (q3) { int j = __builtin_ctzll(q3); q3 &= q3 - 1; Sm = __fadd_rn(Sm, apo[192 + j]); }
                // Sp = fold_{b' in spk(f)} apre[t][b'][i], ascending b' (coalesced in i)
                float Sp = 0.0f;
                u64 m;
                m = s0; while (m) { int j = __builtin_ctzll(m); m &= m - 1;
                                    Sp = __fadd_rn(Sp, at[(size_t)j * NIN + i]); }
                m = s1; while (m) { int j = __builtin_ctzll(m); m &= m - 1;
                                    Sp = __fadd_rn(Sp, at[(size_t)(64 + j) * NIN + i]); }
                m = s2; while (m) { int j = __builtin_ctzll(m); m &= m - 1;
                                    Sp = __fadd_rn(Sp, at[(size_t)(128 + j) * NIN + i]); }
                m = s3; while (m) { int j = __builtin_ctzll(m); m &= m - 1;
                                    Sp = __fadd_rn(Sp, at[(size_t)(192 + j) * NIN + i]); }

                float w = wv[i];
                w = __fadd_rn(w, __fmul_rn(lrp, Sp));
                w = __fsub_rn(w, __fmul_rn(lrm, Sm));
                w = fminf(fmaxf(w, 0.0f), 1.0f);
                wv[i] = w;                  // own element, no conflict
            }
        }
        __syncthreads();               // wv(t+1) visible to next phase A
    }

    out[b * FF + f] = cntv;            // spike counts, exact small ints
}

extern "C" void kernel_launch(void* const* d_in, const int* in_sizes, int n_in,
                              void* d_out, int out_size, void* d_ws, size_t ws_size,
                              hipStream_t stream)
{
    const float* image = (const float*)d_in[0];
    const float* W     = (const float*)d_in[1];
    const float* noise = (const float*)d_in[2];
    float* out = (float*)d_out;

    char* p = (char*)d_ws;
    u64* prebits   = (u64*)p;   p += (size_t)TSTEPS * BB * NW * 8;     // 2.66 MB
    u64* prebitsT  = (u64*)p;   p += (size_t)TSTEPS * NIN * 4 * 8;     // 2.51 MB
    float* apre_all = (float*)p; p += (size_t)TSTEPS * BB * NIN * 4;   // 80.3 MB

    float dmem = (float)exp(-1.0 / 20.0);   // np.float32(np.exp(-0.05))
    float dpre = dmem, dpost = dmem;
    float lrp = (float)(0.01 / 256.0);
    float lrm = (float)(0.012 / 256.0);

    k_encode<<<(TSTEPS * BB * NW * 64) / 256, 256, 0, stream>>>(image, noise, prebits);
    k_encode_t<<<(TSTEPS * NIN * BB) / 256, 256, 0, stream>>>(prebits, prebitsT);
    k_apre<<<(BB * NIN) / 256, 256, 0, stream>>>(prebits, apre_all, dpre);
    k_sim<<<FF, 256, 0, stream>>>(W, prebits, prebitsT, apre_all, out,
                                  dmem, dpost, lrp, lrm);
}